// Round 6
// baseline (410.308 us; speedup 1.0000x reference)
//
#include <hip/hip_runtime.h>

#define BB 512
#define LL 1024
#define TT 52
#define START_TAG 50   // T-2
#define STOP_TAG  51   // T-1
#define NW 4           // waves per batch (i-split)
#define IPW 13         // transition rows per wave
#define CH 16          // steps per chunk (prefetch + renorm period)

__device__ __forceinline__ float rl(float v, int i) {
  return __uint_as_float(__builtin_amdgcn_readlane(__float_as_uint(v), (unsigned)i));
}
__device__ __forceinline__ float wave_max(float v) {
#pragma unroll
  for (int off = 32; off; off >>= 1) v = fmaxf(v, __shfl_xor(v, off, 64));
  return v;
}
__device__ __forceinline__ float wave_sum(float v) {
#pragma unroll
  for (int off = 32; off; off >>= 1) v += __shfl_xor(v, off, 64);
  return v;
}
__device__ __forceinline__ int wave_sum_i(int v) {
#pragma unroll
  for (int off = 32; off; off >>= 1) v += __shfl_xor(v, off, 64);
  return v;
}

// One BLOCK (4 waves) per batch; lane j = tag state j; wave w sums rows
// i in [13w, 13w+13).  Forward recursion in exp space, bias e^-6/step,
// renorm every 16 steps.  Partial sums exchanged through double-buffered
// LDS with ONE raw s_barrier per step (no vmcnt drain -> feats prefetch
// survives the barrier; __syncthreads would drain it).
// R5 established: single-wave issue cadence = 1 instr / 4 cyc, so the
// old 1-wave/batch form was issue-bound at ~135 slots = 540 cyc/step.
__global__ __launch_bounds__(256)
__attribute__((amdgpu_waves_per_eu(2)))
void crf_main(
    const float* __restrict__ feats, const float* __restrict__ trans,
    const void* __restrict__ maskp, const int* __restrict__ tags,
    float* __restrict__ res) {
  __shared__ float xch[2][NW][64];
  const int b = blockIdx.x;
  const int tid = threadIdx.x;
  const int wid = tid >> 6;
  const int lane = tid & 63;
  const bool jok = lane < TT;
  const int j = jok ? lane : TT - 1;        // clamp keeps loads in-bounds
  const int wbase = wid * IPW;

  // ---- length from prefix mask (dtype sniffed; every wave computes the
  // same value from the same row — no exchange needed)
  const unsigned* m32 = (const unsigned*)maskp;
  int s = 0;
  const unsigned v0 = m32[0];
  if (v0 == 0x01010101u) {                  // bool as bytes
    const uint4* mv = (const uint4*)maskp;  // row = 1024 B = 64 uint4
    uint4 x = mv[b * 64 + lane];
    s  = (int)(((x.x & 0x01010101u) * 0x01010101u) >> 24);
    s += (int)(((x.y & 0x01010101u) * 0x01010101u) >> 24);
    s += (int)(((x.z & 0x01010101u) * 0x01010101u) >> 24);
    s += (int)(((x.w & 0x01010101u) * 0x01010101u) >> 24);
  } else if (m32[1] == 0u) {                // int64
    const unsigned long long* m64 = (const unsigned long long*)maskp;
#pragma unroll
    for (int k = 0; k < 16; ++k) s += (int)m64[(size_t)b * LL + k * 64 + lane];
  } else {                                  // int32
    const int* mi = (const int*)maskp;
#pragma unroll
    for (int k = 0; k < 16; ++k) s += mi[b * LL + k * 64 + lane];
  }
  const int len = wave_sum_i(s);            // uniform across all 4 waves

  // ---- this wave's 13 transition rows (col j), named registers
#define EDECL(k) float E##k = jok ? __expf(trans[(wbase + (k)) * TT + j]) : 0.f;
  EDECL(0) EDECL(1) EDECL(2) EDECL(3) EDECL(4) EDECL(5) EDECL(6)
  EDECL(7) EDECL(8) EDECL(9) EDECL(10) EDECL(11) EDECL(12)
#undef EDECL

  const float* fp = feats + (size_t)b * LL * TT + j;
  float p = jok ? __expf(fp[0]) * __expf(trans[START_TAG * TT + j]) : 0.f;
  float carry2 = 0.f;                       // log2 of accumulated renorms

  // one step: 13 broadcasts+FMAs -> partial -> LDS exchange -> combine.
  // PAR is compile-time ((k+1)&1 — tbase is always odd).  All waves combine
  // in the SAME order -> p stays bitwise identical in all 4 waves.
#define CRF_STEP(FV, PAR)                                                \
  {                                                                      \
    const float eft = __expf((FV)-6.0f);                                 \
    const float P0 = rl(p, wbase + 0),  P1 = rl(p, wbase + 1);           \
    const float P2 = rl(p, wbase + 2),  P3 = rl(p, wbase + 3);           \
    const float P4 = rl(p, wbase + 4),  P5 = rl(p, wbase + 5);           \
    const float P6 = rl(p, wbase + 6),  P7 = rl(p, wbase + 7);           \
    const float P8 = rl(p, wbase + 8),  P9 = rl(p, wbase + 9);           \
    const float P10 = rl(p, wbase + 10), P11 = rl(p, wbase + 11);        \
    const float P12 = rl(p, wbase + 12);                                 \
    __builtin_amdgcn_sched_barrier(0);                                   \
    float a0 = P0 * E0, a1 = P1 * E1, a2 = P2 * E2, a3 = P3 * E3;        \
    a0 = fmaf(P4, E4, a0); a1 = fmaf(P5, E5, a1);                        \
    a2 = fmaf(P6, E6, a2); a3 = fmaf(P7, E7, a3);                        \
    a0 = fmaf(P8, E8, a0); a1 = fmaf(P9, E9, a1);                        \
    a2 = fmaf(P10, E10, a2); a3 = fmaf(P11, E11, a3);                    \
    a0 = fmaf(P12, E12, a0);                                             \
    xch[PAR][wid][lane] = (a0 + a1) + (a2 + a3);                         \
    asm volatile("s_waitcnt lgkmcnt(0)" ::: "memory");                   \
    __builtin_amdgcn_s_barrier();                                        \
    const float r0 = xch[PAR][0][lane], r1 = xch[PAR][1][lane];          \
    const float r2 = xch[PAR][2][lane], r3 = xch[PAR][3][lane];          \
    p = ((r0 + r1) + (r2 + r3)) * eft;                                   \
  }

  // keep E resident (cheap belt-and-braces vs remat)
#define EPIN                                                             \
  asm volatile("" : "+v"(E0), "+v"(E1), "+v"(E2), "+v"(E3), "+v"(E4),    \
                    "+v"(E5), "+v"(E6), "+v"(E7), "+v"(E8), "+v"(E9),    \
                    "+v"(E10), "+v"(E11), "+v"(E12));

  const int nsteps = len - 1;               // steps t = 1 .. len-1
  const int nchunk = nsteps / CH;
  const int ntail = nsteps % CH;

  float fb[CH];                             // emissions for current chunk
#pragma unroll
  for (int k = 0; k < CH; ++k) fb[k] = fp[(size_t)(1 + k) * TT];  // len>=512

  int tbase = 1;                            // always odd at chunk start
  for (int c = 0; c < nchunk; ++c) {
    EPIN
    float fn[CH];                           // prefetch next chunk
#pragma unroll
    for (int k = 0; k < CH; ++k) {
      int tt = tbase + CH + k;
      tt = tt < len ? tt : len - 1;         // clamp: harmless in-bounds load
      fn[k] = fp[(size_t)tt * TT];
    }
#pragma unroll
    for (int k = 0; k < CH; ++k) CRF_STEP(fb[k], ((k + 1) & 1));
    const float m = wave_max(p);            // renorm (identical in all waves)
    carry2 += __log2f(m);
    p *= __builtin_amdgcn_rcpf(m);
#pragma unroll
    for (int k = 0; k < CH; ++k) fb[k] = fn[k];
    tbase += CH;
  }
#pragma unroll
  for (int k = 0; k < CH; ++k)              // tail (uniform -> barriers safe)
    if (k < ntail) CRF_STEP(fb[k], ((k + 1) & 1));

  if (wid == 0) {
    // forward score = log(sum p_i e^trans[i,STOP]) + renorms + bias payback
    const float tl = jok ? __expf(trans[j * TT + STOP_TAG]) : 0.f;
    const float sfin = wave_sum(p * tl);
    const float fwd =
        (__log2f(sfin) + carry2) * 0.6931471805599453f + 6.0f * (float)(len - 1);

    // gold score, lane-parallel over time
    const int* tgb = tags + b * LL;
    float g = 0.f;
    for (int base = 0; base < len; base += 64) {
      const int t = base + lane;
      if (t < len) {
        const int tag = tgb[t];
        const int prev = (t == 0) ? START_TAG : tgb[t - 1];
        g += feats[((size_t)b * LL + t) * TT + tag] + trans[prev * TT + tag];
      }
    }
    g = wave_sum(g);

    if (lane == 0) {
      g += trans[tgb[len - 1] * TT + STOP_TAG];
      res[b] = fwd - g;
    }
  }
#undef CRF_STEP
#undef EPIN
}

__global__ __launch_bounds__(64) void crf_fin(const float* __restrict__ res,
                                              float* __restrict__ out) {
  float s = 0.f;
#pragma unroll
  for (int k = 0; k < 8; ++k) s += res[threadIdx.x + k * 64];
  s = wave_sum(s);
  if (threadIdx.x == 0) out[0] = s * (1.0f / (float)BB);
}

extern "C" void kernel_launch(void* const* d_in, const int* in_sizes, int n_in,
                              void* d_out, int out_size, void* d_ws, size_t ws_size,
                              hipStream_t stream) {
  const float* feats = (const float*)d_in[0];
  const float* trans = (const float*)d_in[1];
  const void* mask   = (const void*)d_in[2];
  const int* tags    = (const int*)d_in[3];

  float* res = (float*)d_ws;                // 512 per-batch results

  crf_main<<<BB, NW * 64, 0, stream>>>(feats, trans, mask, tags, res);
  crf_fin<<<1, 64, 0, stream>>>(res, (float*)d_out);
}

// Round 7
// 359.983 us; speedup vs baseline: 1.1398x; 1.1398x over previous
//
#include <hip/hip_runtime.h>

#define BB 512
#define LL 1024
#define TT 52
#define START_TAG 50   // T-2
#define STOP_TAG  51   // T-1
#define CH 16          // steps per chunk (prefetch + renorm period)

typedef __attribute__((ext_vector_type(2))) float f32x2;
typedef __attribute__((ext_vector_type(4))) float f32x4;

__device__ __forceinline__ void pkfma(f32x2& acc, f32x2 a, f32x2 b) {
  // D = S0*S1 + S2  (packed fp32, VOP3P)
  asm("v_pk_fma_f32 %0, %1, %2, %0" : "+v"(acc) : "v"(a), "v"(b));
}

__device__ __forceinline__ float wave_max(float v) {
#pragma unroll
  for (int off = 32; off; off >>= 1) v = fmaxf(v, __shfl_xor(v, off, 64));
  return v;
}
__device__ __forceinline__ float wave_sum(float v) {
#pragma unroll
  for (int off = 32; off; off >>= 1) v += __shfl_xor(v, off, 64);
  return v;
}
__device__ __forceinline__ int wave_sum_i(int v) {
#pragma unroll
  for (int off = 32; off; off >>= 1) v += __shfl_xor(v, off, 64);
  return v;
}

// One wave per batch; lane j = tag state j.  Forward recursion in exp space,
// bias e^-6/step, renorm every 16 steps.
// R5 lesson: single-wave issue cadence ~4cyc/slot -> cut slots/step.
// R6 lesson: cross-wave exchange puts LDS+barrier on the serial chain -> bad.
// This version: intra-wave LDS broadcast of p (1 ds_write + 13 ds_read_b128,
// same-wave in-order DS, no barrier) + 26 v_pk_fma_f32 (input-pair packing)
// replaces 52 readlane + 52 fma:  ~135 -> ~47 slots/step.
__global__ __launch_bounds__(64)
__attribute__((amdgpu_waves_per_eu(1, 1)))
void crf_main(
    const float* __restrict__ feats, const float* __restrict__ trans,
    const void* __restrict__ maskp, const int* __restrict__ tags,
    float* __restrict__ res) {
  __shared__ __align__(16) float pvec[64];
  const int b = blockIdx.x;
  const int lane = threadIdx.x;
  const bool jok = lane < TT;
  const int j = jok ? lane : TT - 1;        // clamp keeps loads in-bounds

  // ---- length from prefix mask (dtype sniffed from content:
  // len>=512 guarantees first elements true; u8->0x01010101, i32->1,1, i64->1,0)
  const unsigned* m32 = (const unsigned*)maskp;
  int s = 0;
  const unsigned v0 = m32[0];
  if (v0 == 0x01010101u) {                  // bool as bytes
    const uint4* mv = (const uint4*)maskp;  // row = 1024 B = 64 uint4
    uint4 x = mv[b * 64 + lane];
    s  = (int)(((x.x & 0x01010101u) * 0x01010101u) >> 24);
    s += (int)(((x.y & 0x01010101u) * 0x01010101u) >> 24);
    s += (int)(((x.z & 0x01010101u) * 0x01010101u) >> 24);
    s += (int)(((x.w & 0x01010101u) * 0x01010101u) >> 24);
  } else if (m32[1] == 0u) {                // int64
    const unsigned long long* m64 = (const unsigned long long*)maskp;
#pragma unroll
    for (int k = 0; k < 16; ++k) s += (int)m64[(size_t)b * LL + k * 64 + lane];
  } else {                                  // int32
    const int* mi = (const int*)maskp;
#pragma unroll
    for (int k = 0; k < 16; ++k) s += mi[b * LL + k * 64 + lane];
  }
  const int len = wave_sum_i(s);            // uniform

  // ---- E column j, input-pair packed: Ek[m] = (E[2m][j], E[2m+1][j])
  f32x2 Ek[26];
#pragma unroll
  for (int m = 0; m < 26; ++m) {
    const float e0 = jok ? __expf(trans[(2 * m) * TT + j]) : 0.f;
    const float e1 = jok ? __expf(trans[(2 * m + 1) * TT + j]) : 0.f;
    Ek[m].x = e0;
    Ek[m].y = e1;
  }

  const float* fp = feats + (size_t)b * LL * TT + j;
  // part0 = f0 + trans[START]  (Ek[25].x = exp(trans[50][j]); 0 for j>=52)
  float p = __expf(fp[0]) * Ek[25].x;
  float carry2 = 0.f;                       // log2 of accumulated renorms

  // one step: write p -> LDS, broadcast-read all 52 as 13 x b128,
  // 26 packed FMAs (2 chains), horizontal add, times emission factor.
#define CRF_STEP(FV)                                                     \
  {                                                                      \
    const float eft = __expf((FV)-6.0f);                                 \
    pvec[lane] = p;                                                      \
    f32x2 aA = {0.f, 0.f}, aB = {0.f, 0.f};                              \
    _Pragma("unroll") for (int m = 0; m < 13; ++m) {                     \
      const f32x4 P4 = *(const f32x4*)&pvec[4 * m];                      \
      pkfma(aA, __builtin_shufflevector(P4, P4, 0, 1), Ek[2 * m]);       \
      pkfma(aB, __builtin_shufflevector(P4, P4, 2, 3), Ek[2 * m + 1]);   \
    }                                                                    \
    const f32x2 aS = aA + aB;                                            \
    p = (aS.x + aS.y) * eft;                                             \
  }

  // keep Ek resident across the chunk loop (budget is 512 via waves_per_eu)
#define EPIN                                                             \
  _Pragma("unroll") for (int m = 0; m < 26; ++m)                         \
      asm volatile("" : "+v"(Ek[m]));

  const int nsteps = len - 1;               // steps t = 1 .. len-1
  const int nchunk = nsteps / CH;
  const int ntail = nsteps % CH;

  float fb[CH];                             // emissions for current chunk
#pragma unroll
  for (int k = 0; k < CH; ++k) fb[k] = fp[(size_t)(1 + k) * TT];  // len>=512

  int tbase = 1;
  for (int c = 0; c < nchunk; ++c) {
    EPIN
    float fn[CH];                           // prefetch next chunk
#pragma unroll
    for (int k = 0; k < CH; ++k) {
      int tt = tbase + CH + k;
      tt = tt < len ? tt : len - 1;         // clamp: harmless in-bounds load
      fn[k] = fp[(size_t)tt * TT];
    }
#pragma unroll
    for (int k = 0; k < CH; ++k) CRF_STEP(fb[k]);
    const float m = wave_max(p);            // renorm every 16 steps
    carry2 += __log2f(m);
    p *= __builtin_amdgcn_rcpf(m);
#pragma unroll
    for (int k = 0; k < CH; ++k) fb[k] = fn[k];
    tbase += CH;
  }
#pragma unroll
  for (int k = 0; k < CH; ++k)              // tail, statically indexed
    if (k < ntail) CRF_STEP(fb[k]);

  // forward score = log(sum p_i * e^trans[i,STOP]) + renorms + bias payback
  const float tl = jok ? __expf(trans[j * TT + STOP_TAG]) : 0.f;
  const float sfin = wave_sum(p * tl);
  const float fwd =
      (__log2f(sfin) + carry2) * 0.6931471805599453f + 6.0f * (float)(len - 1);

  // ---- gold score, lane-parallel over time
  const int* tgb = tags + b * LL;
  float g = 0.f;
  for (int base = 0; base < len; base += 64) {
    const int t = base + lane;
    if (t < len) {
      const int tag = tgb[t];
      const int prev = (t == 0) ? START_TAG : tgb[t - 1];
      g += feats[((size_t)b * LL + t) * TT + tag] + trans[prev * TT + tag];
    }
  }
  g = wave_sum(g);

  if (lane == 0) {
    g += trans[tgb[len - 1] * TT + STOP_TAG];
    res[b] = fwd - g;
  }
#undef CRF_STEP
#undef EPIN
}

__global__ __launch_bounds__(64) void crf_fin(const float* __restrict__ res,
                                              float* __restrict__ out) {
  float s = 0.f;
#pragma unroll
  for (int k = 0; k < 8; ++k) s += res[threadIdx.x + k * 64];
  s = wave_sum(s);
  if (threadIdx.x == 0) out[0] = s * (1.0f / (float)BB);
}

extern "C" void kernel_launch(void* const* d_in, const int* in_sizes, int n_in,
                              void* d_out, int out_size, void* d_ws, size_t ws_size,
                              hipStream_t stream) {
  const float* feats = (const float*)d_in[0];
  const float* trans = (const float*)d_in[1];
  const void* mask   = (const void*)d_in[2];
  const int* tags    = (const int*)d_in[3];

  float* res = (float*)d_ws;                // 512 per-batch results

  crf_main<<<BB, 64, 0, stream>>>(feats, trans, mask, tags, res);
  crf_fin<<<1, 64, 0, stream>>>(res, (float*)d_out);
}